// Round 14
// baseline (400.627 us; speedup 1.0000x reference)
//
#include <hip/hip_runtime.h>
#include <hip/hip_fp16.h>

#define SDIM 1024

typedef _Float16 f16;
typedef _Float16 f16x8 __attribute__((ext_vector_type(8)));
typedef __attribute__((ext_vector_type(4))) float f32x4;

union FragH { unsigned int u[4]; f16x8 f; uint4 q; };

constexpr unsigned short f16bits(float x) {
    return __builtin_bit_cast(unsigned short, (_Float16)x);
}
constexpr unsigned int pk2(float x) {
    return (unsigned int)f16bits(x) * 0x10001u;
}

// 15-instruction trans-free poly gelu (VOP3P only, <=1 SGPR const per instr).
__device__ __forceinline__ unsigned int addgelu_pair(
    unsigned int au, unsigned int bu,
    unsigned int sLo, unsigned int sHi, unsigned int sXA, unsigned int sXB,
    unsigned int sC5, unsigned int sC4, unsigned int sC3, unsigned int sC2,
    unsigned int sC1, unsigned int sC0, unsigned int sHalf)
{
    unsigned int g, t, tc, x, w;
    asm("v_pk_add_f16 %1, %5, %6\n\t"
        "v_pk_max_f16 %2, %1, %7\n\t"
        "v_pk_min_f16 %2, %2, %8\n\t"
        "v_pk_mul_f16 %3, %2, %2\n\t"
        "v_pk_mul_f16 %3, %3, %9\n\t"
        "v_pk_add_f16 %3, %3, %10\n\t"
        "v_pk_mul_f16 %4, %3, %11\n\t"
        "v_pk_add_f16 %4, %4, %12\n\t"
        "v_pk_fma_f16 %4, %4, %3, %13\n\t"
        "v_pk_fma_f16 %4, %4, %3, %14\n\t"
        "v_pk_fma_f16 %4, %4, %3, %15\n\t"
        "v_pk_fma_f16 %4, %4, %3, %16\n\t"
        "v_pk_mul_f16 %4, %4, %2\n\t"
        "v_pk_add_f16 %4, %4, %17\n\t"
        "v_pk_mul_f16 %0, %1, %4"
        : "=v"(g), "=&v"(t), "=&v"(tc), "=&v"(x), "=&v"(w)
        : "v"(au), "v"(bu),
          "s"(sLo), "s"(sHi), "s"(sXA), "s"(sXB),
          "s"(sC5), "s"(sC4), "s"(sC3), "s"(sC2), "s"(sC1), "s"(sC0), "s"(sHalf));
    return g;
}

#define GELU_CONSTS  kLo, kHi, kXA, kXB, kC5, kC4, kC3, kC2, kC1, kC0, kHalf
#define DECL_GELU_CONSTS \
    const unsigned int kLo   = pk2(-3.0f); \
    const unsigned int kHi   = pk2( 3.0f); \
    const unsigned int kXA   = pk2( 2.0f / 9.0f); \
    const unsigned int kXB   = pk2(-1.0f); \
    const unsigned int kC5   = pk2(-0.003456f); \
    const unsigned int kC4   = pk2( 0.009668f); \
    const unsigned int kC3   = pk2(-0.020158f); \
    const unsigned int kC2   = pk2( 0.045110f); \
    const unsigned int kC1   = pk2(-0.092726f); \
    const unsigned int kC0   = pk2( 0.2278245f); \
    const unsigned int kHalf = pk2( 0.5f);

// ---------------- Kernel 1 (unchanged): u,v f16 + W2h = W2^T f16 [16h][64k] ----------
__global__ __launch_bounds__(256) void compute_uv(
    const float* __restrict__ x, const float* __restrict__ Wc,
    const float* __restrict__ bc, const float* __restrict__ W1,
    const float* __restrict__ b1, const float* __restrict__ W2,
    f16* __restrict__ u, f16* __restrict__ v, f16* __restrict__ W2h)
{
    __shared__ float xrow[4 * 1024];
    __shared__ float part[4 * 8 * 32];
    __shared__ float xc[4 * 32];
    const int tid = threadIdx.x;
    const size_t bs0 = (size_t)blockIdx.x * 4;

    if (blockIdx.x == 0) {
        #pragma unroll
        for (int e = 0; e < 4; ++e) {
            const int flat = tid * 4 + e;
            const int h = flat >> 6, k = flat & 63;
            W2h[flat] = (f16)W2[k * 16 + h];
        }
    }
    const float4* xin = (const float4*)(x + bs0 * 1024);
    #pragma unroll
    for (int it = 0; it < 4; ++it)
        ((float4*)xrow)[it * 256 + tid] = xin[it * 256 + tid];
    __syncthreads();
    {
        const int c = tid & 31, p = tid >> 5;
        float acc[4] = {0.f, 0.f, 0.f, 0.f};
        #pragma unroll 4
        for (int dd = 0; dd < 128; ++dd) {
            const int d = p * 128 + dd;
            const float wv = Wc[d * 32 + c];
            #pragma unroll
            for (int r = 0; r < 4; ++r)
                acc[r] = __builtin_fmaf(xrow[r * 1024 + d], wv, acc[r]);
        }
        #pragma unroll
        for (int r = 0; r < 4; ++r)
            part[r * 256 + p * 32 + c] = acc[r];
    }
    __syncthreads();
    if (tid < 128) {
        const int r = tid >> 5, c = tid & 31;
        float s = bc[c];
        #pragma unroll
        for (int p = 0; p < 8; ++p) s += part[r * 256 + p * 32 + c];
        xc[r * 32 + c] = s;
    }
    __syncthreads();
    {
        const int h = tid & 63;
        const int rr = tid >> 6;
        float ua = b1[h], va = 0.0f;
        #pragma unroll
        for (int cc = 0; cc < 32; ++cc) {
            const float xv = xc[rr * 32 + cc];
            ua = __builtin_fmaf(xv, W1[cc * 64 + h], ua);
            va = __builtin_fmaf(xv, W1[(32 + cc) * 64 + h], va);
        }
        u[(bs0 + rr) * 64 + h] = (f16)ua;
        v[(bs0 + rr) * 64 + h] = (f16)va;
    }
}

#define PRG_COMMON_SETUP                                                          \
    const int tid  = threadIdx.x;                                                 \
    const int lane = tid & 63;                                                    \
    const int w    = tid >> 6;                                                    \
    const int jb   = blockIdx.x * 32;                                             \
    const int ib   = blockIdx.y * 32;                                             \
    const int b    = blockIdx.z;                                                  \
    DECL_GELU_CONSTS                                                              \
    __shared__ f16 u_lds[32][64];                                                 \
    {                                                                             \
        const int row = tid >> 3;                                                 \
        const int col = (tid & 7) * 8;                                            \
        *(uint4*)&u_lds[row][col] =                                               \
            *(const uint4*)(u + ((size_t)(b * SDIM + ib + row) * 64 + col));      \
    }                                                                             \
    const int lg = lane >> 4;                                                     \
    const int lr = lane & 15;                                                     \
    const int k0 = lg * 8;                                                        \
    const int jw = jb + (w & 1) * 16;                                             \
    const int iw = (w >> 1) * 16;                                                 \
    const f16* vp = v + ((size_t)(b * SDIM + jw + lr) * 64);                      \
    const uint4 vlo = *(const uint4*)(vp + k0);                                   \
    const uint4 vhi = *(const uint4*)(vp + k0 + 32);

#define GM(IL, ACC)                                                               \
    {                                                                             \
        const uint4 alo = *(const uint4*)&u_lds[IL][k0];                          \
        const uint4 ahi = *(const uint4*)&u_lds[IL][k0 + 32];                     \
        FragH glo, ghi;                                                           \
        glo.u[0] = addgelu_pair(alo.x, vloX.x, GELU_CONSTS);                      \
        glo.u[1] = addgelu_pair(alo.y, vloX.y, GELU_CONSTS);                      \
        glo.u[2] = addgelu_pair(alo.z, vloX.z, GELU_CONSTS);                      \
        glo.u[3] = addgelu_pair(alo.w, vloX.w, GELU_CONSTS);                      \
        ghi.u[0] = addgelu_pair(ahi.x, vhiX.x, GELU_CONSTS);                      \
        ghi.u[1] = addgelu_pair(ahi.y, vhiX.y, GELU_CONSTS);                      \
        ghi.u[2] = addgelu_pair(ahi.z, vhiX.z, GELU_CONSTS);                      \
        ghi.u[3] = addgelu_pair(ahi.w, vhiX.w, GELU_CONSTS);                      \
        f32x4 a_ = {b2h, b2h, b2h, b2h};                                          \
        a_ = __builtin_amdgcn_mfma_f32_16x16x32_f16(glo.f, w2lo.f, a_, 0, 0, 0);  \
        a_ = __builtin_amdgcn_mfma_f32_16x16x32_f16(ghi.f, w2hi.f, a_, 0, 0, 0);  \
        ACC = a_;                                                                 \
    }
#define ST(IL, ACC) *(float4*)(ob + (size_t)(IL) * SDIM) = *(float4*)&(ACC);

// ---- prg_pipe: 2-deep acc pipeline; store issued after NEXT il's compute ----
__global__ __launch_bounds__(256) void prg_pipe(
    const f16* __restrict__ u, const f16* __restrict__ v,
    const f16* __restrict__ W2h, const float* __restrict__ b2,
    float* __restrict__ out, int reps)
{
    PRG_COMMON_SETUP
    FragH w2lo, w2hi;
    w2lo.q = *(const uint4*)(W2h + lr * 64 + k0);
    w2hi.q = *(const uint4*)(W2h + lr * 64 + k0 + 32);
    const float b2h = b2[lr];
    __syncthreads();

    float* ob = out + ((size_t)(b * 16 + lr) * SDIM + (ib + iw)) * SDIM + jw + lg * 4;
    unsigned int seed = tid;

    for (int rep = 0; rep < reps; ++rep) {
        unsigned int z;   // opaque zero (defeats rep-loop hoisting; no-op at runtime)
        asm("v_and_b32 %0, 0, %1" : "=v"(z) : "v"(seed));
        const uint4 vloX = {vlo.x ^ z, vlo.y ^ z, vlo.z ^ z, vlo.w ^ z};
        const uint4 vhiX = {vhi.x ^ z, vhi.y ^ z, vhi.z ^ z, vhi.w ^ z};

        f32x4 accA, accB;
        GM(iw + 0, accA)
        #pragma unroll
        for (int p = 0; p < 7; ++p) {
            GM(iw + 2 * p + 1, accB)
            ST(2 * p, accA)
            GM(iw + 2 * p + 2, accA)
            ST(2 * p + 1, accB)
        }
        GM(iw + 15, accB)
        ST(14, accA)
        ST(15, accB)
        seed ^= __float_as_uint(accB[3]);   // loop-carried dep across reps
    }
}

// ---- prg_valu: pure gelu-chain rate microbench (no MFMA, no bulk stores) ----
__global__ __launch_bounds__(256) void prg_valu(
    const f16* __restrict__ u, const f16* __restrict__ v,
    unsigned int* __restrict__ outu, int reps)
{
    PRG_COMMON_SETUP
    __syncthreads();
    unsigned int seed = tid;

    for (int rep = 0; rep < reps; ++rep) {
        unsigned int z;
        asm("v_and_b32 %0, 0, %1" : "=v"(z) : "v"(seed));
        const uint4 vloX = {vlo.x ^ z, vlo.y ^ z, vlo.z ^ z, vlo.w ^ z};
        const uint4 vhiX = {vhi.x ^ z, vhi.y ^ z, vhi.z ^ z, vhi.w ^ z};
        unsigned int acc = 0;
        #pragma unroll
        for (int il = 0; il < 16; ++il) {
            const uint4 alo = *(const uint4*)&u_lds[iw + il][k0];
            const uint4 ahi = *(const uint4*)&u_lds[iw + il][k0 + 32];
            acc ^= addgelu_pair(alo.x, vloX.x, GELU_CONSTS);
            acc ^= addgelu_pair(alo.y, vloX.y, GELU_CONSTS);
            acc ^= addgelu_pair(alo.z, vloX.z, GELU_CONSTS);
            acc ^= addgelu_pair(alo.w, vloX.w, GELU_CONSTS);
            acc ^= addgelu_pair(ahi.x, vhiX.x, GELU_CONSTS);
            acc ^= addgelu_pair(ahi.y, vhiX.y, GELU_CONSTS);
            acc ^= addgelu_pair(ahi.z, vhiX.z, GELU_CONSTS);
            acc ^= addgelu_pair(ahi.w, vhiX.w, GELU_CONSTS);
        }
        seed ^= acc;
    }
    const size_t bid = (blockIdx.z * gridDim.y + blockIdx.y) * gridDim.x + blockIdx.x;
    outu[bid * 256 + tid] = seed;   // in-bounds scratch region of out; final pass rewrites
}

extern "C" void kernel_launch(void* const* d_in, const int* in_sizes, int n_in,
                              void* d_out, int out_size, void* d_ws, size_t ws_size,
                              hipStream_t stream) {
    const float* x  = (const float*)d_in[0];
    const float* Wc = (const float*)d_in[1];
    const float* bc = (const float*)d_in[2];
    const float* W1 = (const float*)d_in[3];
    const float* b1 = (const float*)d_in[4];
    const float* W2 = (const float*)d_in[5];
    const float* b2 = (const float*)d_in[6];
    float* out = (float*)d_out;

    f16* u   = (f16*)d_ws;
    f16* v   = u + 2 * SDIM * 64;
    f16* W2h = v + 2 * SDIM * 64;

    compute_uv<<<dim3(512), dim3(256), 0, stream>>>(x, Wc, bc, W1, b1, W2, u, v, W2h);

    const dim3 grid(32, 32, 2), blk(256);
    // Diagnostics (out overwritten by the final pass):
    prg_valu<<<grid, blk, 0, stream>>>(u, v, (unsigned int*)out, 8);   // gelu-chain rate
    prg_pipe<<<grid, blk, 0, stream>>>(u, v, W2h, b2, out, 4);         // pipelined, counters
    // Final correct pass:
    prg_pipe<<<grid, blk, 0, stream>>>(u, v, W2h, b2, out, 1);
}

// Round 16
// 58.252 us; speedup vs baseline: 6.8775x; 6.8775x over previous
//
#include <hip/hip_runtime.h>
#include <hip/hip_fp16.h>

#define SDIM 1024

typedef _Float16 f16;
typedef _Float16 f16x8 __attribute__((ext_vector_type(8)));
typedef __fp16 fp16x2 __attribute__((ext_vector_type(2)));
typedef __attribute__((ext_vector_type(4))) float f32x4;

union FragH { unsigned int u[4]; f16x8 f; uint4 q; };

// f32 gelu core: tc = med3(t,-3,3); s = tc^2; x = s*(2/9)-1;
// w = poly5(x) (pre-halved coeffs); sigma = 0.5 + tc*w; g = t*sigma.
// 10 f32 VALU ops @2cy vs the pk-f16 path's 4cy/instr (measured R14: v_pk ~4cy).
__device__ __forceinline__ float gelu_core(float t) {
    float tc = __builtin_amdgcn_fmed3f(t, -3.0f, 3.0f);
    float s  = tc * tc;
    float x  = __builtin_fmaf(s, 0.2222222f, -1.0f);
    float w  = __builtin_fmaf(-0.003456f, x, 0.009668f);
    w = __builtin_fmaf(w, x, -0.020158f);
    w = __builtin_fmaf(w, x,  0.045110f);
    w = __builtin_fmaf(w, x, -0.092726f);
    w = __builtin_fmaf(w, x,  0.2278245f);
    float sg = __builtin_fmaf(tc, w, 0.5f);
    return t * sg;
}

// pair: pk_add (f16) -> split -> 2x f32 core -> cvt_pkrtz repack. ~52cy/pair.
__device__ __forceinline__ unsigned int addgelu_pair(unsigned int au, unsigned int bu) {
    union { unsigned int u; __half2 h; } A, B, T;
    A.u = au; B.u = bu;
    T.h = __hadd2(A.h, B.h);                         // v_pk_add_f16
    const float tl = (float)__builtin_bit_cast(f16, (unsigned short)(T.u & 0xFFFFu));
    const float th = (float)__builtin_bit_cast(f16, (unsigned short)(T.u >> 16));
    const float gl = gelu_core(tl);
    const float gh = gelu_core(th);
    fp16x2 p = __builtin_amdgcn_cvt_pkrtz(gl, gh);   // v_cvt_pkrtz_f16_f32
    return __builtin_bit_cast(unsigned int, p);
}

// ---------------- Kernel 1: u,v f16 + W2h = W2^T f16 [16h][64k] ----------------
__global__ __launch_bounds__(256) void compute_uv(
    const float* __restrict__ x, const float* __restrict__ Wc,
    const float* __restrict__ bc, const float* __restrict__ W1,
    const float* __restrict__ b1, const float* __restrict__ W2,
    f16* __restrict__ u, f16* __restrict__ v, f16* __restrict__ W2h)
{
    __shared__ float xrow[4 * 1024];
    __shared__ float part[4 * 8 * 32];
    __shared__ float xc[4 * 32];
    const int tid = threadIdx.x;
    const size_t bs0 = (size_t)blockIdx.x * 4;

    if (blockIdx.x == 0) {
        #pragma unroll
        for (int e = 0; e < 4; ++e) {
            const int flat = tid * 4 + e;
            const int h = flat >> 6, k = flat & 63;
            W2h[flat] = (f16)W2[k * 16 + h];
        }
    }
    const float4* xin = (const float4*)(x + bs0 * 1024);
    #pragma unroll
    for (int it = 0; it < 4; ++it)
        ((float4*)xrow)[it * 256 + tid] = xin[it * 256 + tid];
    __syncthreads();
    {
        const int c = tid & 31, p = tid >> 5;
        float acc[4] = {0.f, 0.f, 0.f, 0.f};
        #pragma unroll 4
        for (int dd = 0; dd < 128; ++dd) {
            const int d = p * 128 + dd;
            const float wv = Wc[d * 32 + c];
            #pragma unroll
            for (int r = 0; r < 4; ++r)
                acc[r] = __builtin_fmaf(xrow[r * 1024 + d], wv, acc[r]);
        }
        #pragma unroll
        for (int r = 0; r < 4; ++r)
            part[r * 256 + p * 32 + c] = acc[r];
    }
    __syncthreads();
    if (tid < 128) {
        const int r = tid >> 5, c = tid & 31;
        float s = bc[c];
        #pragma unroll
        for (int p = 0; p < 8; ++p) s += part[r * 256 + p * 32 + c];
        xc[r * 32 + c] = s;
    }
    __syncthreads();
    {
        const int h = tid & 63;
        const int rr = tid >> 6;
        float ua = b1[h], va = 0.0f;
        #pragma unroll
        for (int cc = 0; cc < 32; ++cc) {
            const float xv = xc[rr * 32 + cc];
            ua = __builtin_fmaf(xv, W1[cc * 64 + h], ua);
            va = __builtin_fmaf(xv, W1[(32 + cc) * 64 + h], va);
        }
        u[(bs0 + rr) * 64 + h] = (f16)ua;
        v[(bs0 + rr) * 64 + h] = (f16)va;
    }
}

// ---------------- Kernel 2: out[b,h,i,j] = sum_k gelu(u[i,k]+v[j,k])*W2[k,h] + b2[h] --
// R14's proven prg_pipe structure (2-deep acc pipeline: store issued after the NEXT
// il's compute -> stores stay in flight under VALU; measured ~26us/rep at the pk
// VALU floor). 32i x 32j tile, 4 waves, grid (32,32,2) = 2048 blocks.
__global__ __launch_bounds__(256) void prg_main(
    const f16* __restrict__ u, const f16* __restrict__ v,
    const f16* __restrict__ W2h, const float* __restrict__ b2,
    float* __restrict__ out)
{
    const int tid  = threadIdx.x;
    const int lane = tid & 63;
    const int w    = tid >> 6;
    const int jb   = blockIdx.x * 32;
    const int ib   = blockIdx.y * 32;
    const int b    = blockIdx.z;

    __shared__ f16 u_lds[32][64];   // 4 KB

    {
        const int row = tid >> 3;
        const int col = (tid & 7) * 8;
        *(uint4*)&u_lds[row][col] =
            *(const uint4*)(u + ((size_t)(b * SDIM + ib + row) * 64 + col));
    }

    const int lg = lane >> 4;
    const int lr = lane & 15;
    const int k0 = lg * 8;
    const int jw = jb + (w & 1) * 16;
    const int iw = (w >> 1) * 16;

    const f16* vp = v + ((size_t)(b * SDIM + jw + lr) * 64);
    const uint4 vlo = *(const uint4*)(vp + k0);
    const uint4 vhi = *(const uint4*)(vp + k0 + 32);

    FragH w2lo, w2hi;
    w2lo.q = *(const uint4*)(W2h + lr * 64 + k0);
    w2hi.q = *(const uint4*)(W2h + lr * 64 + k0 + 32);

    const float b2h = b2[lr];

    __syncthreads();

    float* ob = out + ((size_t)(b * 16 + lr) * SDIM + (ib + iw)) * SDIM + jw + lg * 4;

#define GM(IL, ACC)                                                               \
    {                                                                             \
        const uint4 alo = *(const uint4*)&u_lds[IL][k0];                          \
        const uint4 ahi = *(const uint4*)&u_lds[IL][k0 + 32];                     \
        FragH glo, ghi;                                                           \
        glo.u[0] = addgelu_pair(alo.x, vlo.x);                                    \
        glo.u[1] = addgelu_pair(alo.y, vlo.y);                                    \
        glo.u[2] = addgelu_pair(alo.z, vlo.z);                                    \
        glo.u[3] = addgelu_pair(alo.w, vlo.w);                                    \
        ghi.u[0] = addgelu_pair(ahi.x, vhi.x);                                    \
        ghi.u[1] = addgelu_pair(ahi.y, vhi.y);                                    \
        ghi.u[2] = addgelu_pair(ahi.z, vhi.z);                                    \
        ghi.u[3] = addgelu_pair(ahi.w, vhi.w);                                    \
        f32x4 a_ = {b2h, b2h, b2h, b2h};                                          \
        a_ = __builtin_amdgcn_mfma_f32_16x16x32_f16(glo.f, w2lo.f, a_, 0, 0, 0);  \
        a_ = __builtin_amdgcn_mfma_f32_16x16x32_f16(ghi.f, w2hi.f, a_, 0, 0, 0);  \
        ACC = a_;                                                                 \
    }
#define ST(IL, ACC) *(float4*)(ob + (size_t)(IL) * SDIM) = *(float4*)&(ACC);

    f32x4 accA, accB;
    GM(iw + 0, accA)
    #pragma unroll
    for (int p = 0; p < 7; ++p) {
        GM(iw + 2 * p + 1, accB)
        ST(2 * p, accA)
        GM(iw + 2 * p + 2, accA)
        ST(2 * p + 1, accB)
    }
    GM(iw + 15, accB)
    ST(14, accA)
    ST(15, accB)
#undef GM
#undef ST
}

extern "C" void kernel_launch(void* const* d_in, const int* in_sizes, int n_in,
                              void* d_out, int out_size, void* d_ws, size_t ws_size,
                              hipStream_t stream) {
    const float* x  = (const float*)d_in[0];
    const float* Wc = (const float*)d_in[1];
    const float* bc = (const float*)d_in[2];
    const float* W1 = (const float*)d_in[3];
    const float* b1 = (const float*)d_in[4];
    const float* W2 = (const float*)d_in[5];
    const float* b2 = (const float*)d_in[6];
    float* out = (float*)d_out;

    f16* u   = (f16*)d_ws;
    f16* v   = u + 2 * SDIM * 64;
    f16* W2h = v + 2 * SDIM * 64;

    compute_uv<<<dim3(512), dim3(256), 0, stream>>>(x, Wc, bc, W1, b1, W2, u, v, W2h);
    prg_main<<<dim3(32, 32, 2), dim3(256), 0, stream>>>(u, v, W2h, b2, out);
}

// Round 17
// 51.556 us; speedup vs baseline: 7.7707x; 1.1299x over previous
//
#include <hip/hip_runtime.h>
#include <hip/hip_fp16.h>

#define SDIM 1024

typedef _Float16 f16;
typedef _Float16 f16x8 __attribute__((ext_vector_type(8)));
typedef __attribute__((ext_vector_type(4))) float f32x4;

union FragH { unsigned int u[4]; f16x8 f; uint4 q; };

constexpr unsigned short f16bits(float x) {
    return __builtin_bit_cast(unsigned short, (_Float16)x);
}
constexpr unsigned int pk2(float x) {
    return (unsigned int)f16bits(x) * 0x10001u;
}

// 15-instruction trans-free poly gelu (VOP3P only, <=1 SGPR const per instr).
// Measured (R14): in the 2-deep pipe this runs at 26.5us/rep for the full tile.
__device__ __forceinline__ unsigned int addgelu_pair(
    unsigned int au, unsigned int bu,
    unsigned int sLo, unsigned int sHi, unsigned int sXA, unsigned int sXB,
    unsigned int sC5, unsigned int sC4, unsigned int sC3, unsigned int sC2,
    unsigned int sC1, unsigned int sC0, unsigned int sHalf)
{
    unsigned int g, t, tc, x, w;
    asm("v_pk_add_f16 %1, %5, %6\n\t"
        "v_pk_max_f16 %2, %1, %7\n\t"
        "v_pk_min_f16 %2, %2, %8\n\t"
        "v_pk_mul_f16 %3, %2, %2\n\t"
        "v_pk_mul_f16 %3, %3, %9\n\t"
        "v_pk_add_f16 %3, %3, %10\n\t"
        "v_pk_mul_f16 %4, %3, %11\n\t"
        "v_pk_add_f16 %4, %4, %12\n\t"
        "v_pk_fma_f16 %4, %4, %3, %13\n\t"
        "v_pk_fma_f16 %4, %4, %3, %14\n\t"
        "v_pk_fma_f16 %4, %4, %3, %15\n\t"
        "v_pk_fma_f16 %4, %4, %3, %16\n\t"
        "v_pk_mul_f16 %4, %4, %2\n\t"
        "v_pk_add_f16 %4, %4, %17\n\t"
        "v_pk_mul_f16 %0, %1, %4"
        : "=v"(g), "=&v"(t), "=&v"(tc), "=&v"(x), "=&v"(w)
        : "v"(au), "v"(bu),
          "s"(sLo), "s"(sHi), "s"(sXA), "s"(sXB),
          "s"(sC5), "s"(sC4), "s"(sC3), "s"(sC2), "s"(sC1), "s"(sC0), "s"(sHalf));
    return g;
}

#define GELU_CONSTS  kLo, kHi, kXA, kXB, kC5, kC4, kC3, kC2, kC1, kC0, kHalf
#define DECL_GELU_CONSTS \
    const unsigned int kLo   = pk2(-3.0f); \
    const unsigned int kHi   = pk2( 3.0f); \
    const unsigned int kXA   = pk2( 2.0f / 9.0f); \
    const unsigned int kXB   = pk2(-1.0f); \
    const unsigned int kC5   = pk2(-0.003456f); \
    const unsigned int kC4   = pk2( 0.009668f); \
    const unsigned int kC3   = pk2(-0.020158f); \
    const unsigned int kC2   = pk2( 0.045110f); \
    const unsigned int kC1   = pk2(-0.092726f); \
    const unsigned int kC0   = pk2( 0.2278245f); \
    const unsigned int kHalf = pk2( 0.5f);

// ---------------- Kernel 1: u,v f16 + W2h = W2^T f16 [16h][64k] ----------------
__global__ __launch_bounds__(256) void compute_uv(
    const float* __restrict__ x, const float* __restrict__ Wc,
    const float* __restrict__ bc, const float* __restrict__ W1,
    const float* __restrict__ b1, const float* __restrict__ W2,
    f16* __restrict__ u, f16* __restrict__ v, f16* __restrict__ W2h)
{
    __shared__ float xrow[4 * 1024];
    __shared__ float part[4 * 8 * 32];
    __shared__ float xc[4 * 32];
    const int tid = threadIdx.x;
    const size_t bs0 = (size_t)blockIdx.x * 4;

    if (blockIdx.x == 0) {
        #pragma unroll
        for (int e = 0; e < 4; ++e) {
            const int flat = tid * 4 + e;
            const int h = flat >> 6, k = flat & 63;
            W2h[flat] = (f16)W2[k * 16 + h];
        }
    }
    const float4* xin = (const float4*)(x + bs0 * 1024);
    #pragma unroll
    for (int it = 0; it < 4; ++it)
        ((float4*)xrow)[it * 256 + tid] = xin[it * 256 + tid];
    __syncthreads();
    {
        const int c = tid & 31, p = tid >> 5;
        float acc[4] = {0.f, 0.f, 0.f, 0.f};
        #pragma unroll 4
        for (int dd = 0; dd < 128; ++dd) {
            const int d = p * 128 + dd;
            const float wv = Wc[d * 32 + c];
            #pragma unroll
            for (int r = 0; r < 4; ++r)
                acc[r] = __builtin_fmaf(xrow[r * 1024 + d], wv, acc[r]);
        }
        #pragma unroll
        for (int r = 0; r < 4; ++r)
            part[r * 256 + p * 32 + c] = acc[r];
    }
    __syncthreads();
    if (tid < 128) {
        const int r = tid >> 5, c = tid & 31;
        float s = bc[c];
        #pragma unroll
        for (int p = 0; p < 8; ++p) s += part[r * 256 + p * 32 + c];
        xc[r * 32 + c] = s;
    }
    __syncthreads();
    {
        const int h = tid & 63;
        const int rr = tid >> 6;
        float ua = b1[h], va = 0.0f;
        #pragma unroll
        for (int cc = 0; cc < 32; ++cc) {
            const float xv = xc[rr * 32 + cc];
            ua = __builtin_fmaf(xv, W1[cc * 64 + h], ua);
            va = __builtin_fmaf(xv, W1[(32 + cc) * 64 + h], va);
        }
        u[(bs0 + rr) * 64 + h] = (f16)ua;
        v[(bs0 + rr) * 64 + h] = (f16)va;
    }
}

// ---------------- Kernel 2: R14's prg_pipe, single-pass ----------------
// out[b,h,i,j] = sum_k gelu(u[i,k]+v[j,k])*W2[k,h] + b2[h]
// 32i x 32j tile, 4 waves, grid (32,32,2). 2-deep acc pipeline: each store is
// issued after the NEXT il's compute, so stores stay in flight under VALU
// (measured 26.5us/rep in R14 vs 47us serialized in R13).
__global__ __launch_bounds__(256) void prg_main(
    const f16* __restrict__ u, const f16* __restrict__ v,
    const f16* __restrict__ W2h, const float* __restrict__ b2,
    float* __restrict__ out)
{
    const int tid  = threadIdx.x;
    const int lane = tid & 63;
    const int w    = tid >> 6;
    const int jb   = blockIdx.x * 32;
    const int ib   = blockIdx.y * 32;
    const int b    = blockIdx.z;

    DECL_GELU_CONSTS

    __shared__ f16 u_lds[32][64];   // 4 KB

    {
        const int row = tid >> 3;
        const int col = (tid & 7) * 8;
        *(uint4*)&u_lds[row][col] =
            *(const uint4*)(u + ((size_t)(b * SDIM + ib + row) * 64 + col));
    }

    const int lg = lane >> 4;
    const int lr = lane & 15;
    const int k0 = lg * 8;
    const int jw = jb + (w & 1) * 16;
    const int iw = (w >> 1) * 16;

    const f16* vp = v + ((size_t)(b * SDIM + jw + lr) * 64);
    const uint4 vlo = *(const uint4*)(vp + k0);
    const uint4 vhi = *(const uint4*)(vp + k0 + 32);

    FragH w2lo, w2hi;
    w2lo.q = *(const uint4*)(W2h + lr * 64 + k0);
    w2hi.q = *(const uint4*)(W2h + lr * 64 + k0 + 32);

    const float b2h = b2[lr];

    __syncthreads();

    float* ob = out + ((size_t)(b * 16 + lr) * SDIM + (ib + iw)) * SDIM + jw + lg * 4;

#define GM(IL, ACC)                                                               \
    {                                                                             \
        const uint4 alo = *(const uint4*)&u_lds[IL][k0];                          \
        const uint4 ahi = *(const uint4*)&u_lds[IL][k0 + 32];                     \
        FragH glo, ghi;                                                           \
        glo.u[0] = addgelu_pair(alo.x, vlo.x, GELU_CONSTS);                       \
        glo.u[1] = addgelu_pair(alo.y, vlo.y, GELU_CONSTS);                       \
        glo.u[2] = addgelu_pair(alo.z, vlo.z, GELU_CONSTS);                       \
        glo.u[3] = addgelu_pair(alo.w, vlo.w, GELU_CONSTS);                       \
        ghi.u[0] = addgelu_pair(ahi.x, vhi.x, GELU_CONSTS);                       \
        ghi.u[1] = addgelu_pair(ahi.y, vhi.y, GELU_CONSTS);                       \
        ghi.u[2] = addgelu_pair(ahi.z, vhi.z, GELU_CONSTS);                       \
        ghi.u[3] = addgelu_pair(ahi.w, vhi.w, GELU_CONSTS);                       \
        f32x4 a_ = {b2h, b2h, b2h, b2h};                                          \
        a_ = __builtin_amdgcn_mfma_f32_16x16x32_f16(glo.f, w2lo.f, a_, 0, 0, 0);  \
        a_ = __builtin_amdgcn_mfma_f32_16x16x32_f16(ghi.f, w2hi.f, a_, 0, 0, 0);  \
        ACC = a_;                                                                 \
    }
#define ST(IL, ACC) *(float4*)(ob + (size_t)(IL) * SDIM) = *(float4*)&(ACC);

    f32x4 accA, accB;
    GM(iw + 0, accA)
    #pragma unroll
    for (int p = 0; p < 7; ++p) {
        GM(iw + 2 * p + 1, accB)
        ST(2 * p, accA)
        GM(iw + 2 * p + 2, accA)
        ST(2 * p + 1, accB)
    }
    GM(iw + 15, accB)
    ST(14, accA)
    ST(15, accB)
#undef GM
#undef ST
}

extern "C" void kernel_launch(void* const* d_in, const int* in_sizes, int n_in,
                              void* d_out, int out_size, void* d_ws, size_t ws_size,
                              hipStream_t stream) {
    const float* x  = (const float*)d_in[0];
    const float* Wc = (const float*)d_in[1];
    const float* bc = (const float*)d_in[2];
    const float* W1 = (const float*)d_in[3];
    const float* b1 = (const float*)d_in[4];
    const float* W2 = (const float*)d_in[5];
    const float* b2 = (const float*)d_in[6];
    float* out = (float*)d_out;

    f16* u   = (f16*)d_ws;
    f16* v   = u + 2 * SDIM * 64;
    f16* W2h = v + 2 * SDIM * 64;

    compute_uv<<<dim3(512), dim3(256), 0, stream>>>(x, Wc, bc, W1, b1, W2, u, v, W2h);
    prg_main<<<dim3(32, 32, 2), dim3(256), 0, stream>>>(u, v, W2h, b2, out);
}

// Round 18
// 47.099 us; speedup vs baseline: 8.5061x; 1.0946x over previous
//
#include <hip/hip_runtime.h>
#include <hip/hip_fp16.h>

#define SDIM 1024

typedef _Float16 f16;
typedef _Float16 f16x8 __attribute__((ext_vector_type(8)));
typedef __attribute__((ext_vector_type(4))) float f32x4;

union FragH { unsigned int u[4]; f16x8 f; uint4 q; };

constexpr unsigned short f16bits(float x) {
    return __builtin_bit_cast(unsigned short, (_Float16)x);
}
constexpr unsigned int pk2(float x) {
    return (unsigned int)f16bits(x) * 0x10001u;
}

// 12-instruction trans-free poly gelu (was 15): mul+add pairs folded into pk_fma.
// Two fmas need 2 constants -> 2nd constant passed in a VGPR (VOP3P allows only
// one SGPR read per instruction). 48cy/pair at the measured 4cy/v_pk rate.
__device__ __forceinline__ unsigned int addgelu_pair(
    unsigned int au, unsigned int bu,
    unsigned int sLo, unsigned int sHi, unsigned int sXA, unsigned int vXB,
    unsigned int sC5, unsigned int vC4, unsigned int sC3, unsigned int sC2,
    unsigned int sC1, unsigned int sC0, unsigned int sHalf)
{
    unsigned int g, t, tc, x, w;
    asm("v_pk_add_f16 %1, %5, %6\n\t"          // t  = a + b
        "v_pk_max_f16 %2, %1, %7\n\t"          // tc = max(t,-3)
        "v_pk_min_f16 %2, %2, %8\n\t"          // tc = min(tc,3)
        "v_pk_mul_f16 %3, %2, %2\n\t"          // s  = tc*tc
        "v_pk_fma_f16 %3, %3, %9, %10\n\t"     // x  = s*(2/9) + (-1)
        "v_pk_fma_f16 %4, %3, %11, %12\n\t"    // w  = x*C5 + C4
        "v_pk_fma_f16 %4, %4, %3, %13\n\t"     // w  = w*x + C3
        "v_pk_fma_f16 %4, %4, %3, %14\n\t"     //            + C2
        "v_pk_fma_f16 %4, %4, %3, %15\n\t"     //            + C1
        "v_pk_fma_f16 %4, %4, %3, %16\n\t"     //            + C0
        "v_pk_fma_f16 %4, %4, %2, %17\n\t"     // sg = w*tc + 0.5
        "v_pk_mul_f16 %0, %1, %4"              // g  = t*sg
        : "=v"(g), "=&v"(t), "=&v"(tc), "=&v"(x), "=&v"(w)
        : "v"(au), "v"(bu),
          "s"(sLo), "s"(sHi), "s"(sXA), "v"(vXB),
          "s"(sC5), "v"(vC4), "s"(sC3), "s"(sC2), "s"(sC1), "s"(sC0), "s"(sHalf));
    return g;
}

#define GELU_CONSTS  kLo, kHi, kXA, kXB, kC5, kC4, kC3, kC2, kC1, kC0, kHalf
#define DECL_GELU_CONSTS \
    const unsigned int kLo   = pk2(-3.0f); \
    const unsigned int kHi   = pk2( 3.0f); \
    const unsigned int kXA   = pk2( 2.0f / 9.0f); \
    const unsigned int kXB   = pk2(-1.0f); \
    const unsigned int kC5   = pk2(-0.003456f); \
    const unsigned int kC4   = pk2( 0.009668f); \
    const unsigned int kC3   = pk2(-0.020158f); \
    const unsigned int kC2   = pk2( 0.045110f); \
    const unsigned int kC1   = pk2(-0.092726f); \
    const unsigned int kC0   = pk2( 0.2278245f); \
    const unsigned int kHalf = pk2( 0.5f);

// ---------------- Kernel 1: u,v f16 + W2h = W2^T f16 [16h][64k] ----------------
__global__ __launch_bounds__(256) void compute_uv(
    const float* __restrict__ x, const float* __restrict__ Wc,
    const float* __restrict__ bc, const float* __restrict__ W1,
    const float* __restrict__ b1, const float* __restrict__ W2,
    f16* __restrict__ u, f16* __restrict__ v, f16* __restrict__ W2h)
{
    __shared__ float xrow[4 * 1024];
    __shared__ float part[4 * 8 * 32];
    __shared__ float xc[4 * 32];
    const int tid = threadIdx.x;
    const size_t bs0 = (size_t)blockIdx.x * 4;

    if (blockIdx.x == 0) {
        #pragma unroll
        for (int e = 0; e < 4; ++e) {
            const int flat = tid * 4 + e;
            const int h = flat >> 6, k = flat & 63;
            W2h[flat] = (f16)W2[k * 16 + h];
        }
    }
    const float4* xin = (const float4*)(x + bs0 * 1024);
    #pragma unroll
    for (int it = 0; it < 4; ++it)
        ((float4*)xrow)[it * 256 + tid] = xin[it * 256 + tid];
    __syncthreads();
    {
        const int c = tid & 31, p = tid >> 5;
        float acc[4] = {0.f, 0.f, 0.f, 0.f};
        #pragma unroll 4
        for (int dd = 0; dd < 128; ++dd) {
            const int d = p * 128 + dd;
            const float wv = Wc[d * 32 + c];
            #pragma unroll
            for (int r = 0; r < 4; ++r)
                acc[r] = __builtin_fmaf(xrow[r * 1024 + d], wv, acc[r]);
        }
        #pragma unroll
        for (int r = 0; r < 4; ++r)
            part[r * 256 + p * 32 + c] = acc[r];
    }
    __syncthreads();
    if (tid < 128) {
        const int r = tid >> 5, c = tid & 31;
        float s = bc[c];
        #pragma unroll
        for (int p = 0; p < 8; ++p) s += part[r * 256 + p * 32 + c];
        xc[r * 32 + c] = s;
    }
    __syncthreads();
    {
        const int h = tid & 63;
        const int rr = tid >> 6;
        float ua = b1[h], va = 0.0f;
        #pragma unroll
        for (int cc = 0; cc < 32; ++cc) {
            const float xv = xc[rr * 32 + cc];
            ua = __builtin_fmaf(xv, W1[cc * 64 + h], ua);
            va = __builtin_fmaf(xv, W1[(32 + cc) * 64 + h], va);
        }
        u[(bs0 + rr) * 64 + h] = (f16)ua;
        v[(bs0 + rr) * 64 + h] = (f16)va;
    }
}

// ---------------- Kernel 2: out[b,h,i,j] = sum_k gelu(u[i,k]+v[j,k])*W2[k,h] + b2[h] --
// 64i x 64j tile, 512 threads = 8 waves (wave w: j-frag w&3, i-half w>>2), 32 ils
// per wave with 2-deep acc pipeline. Grid (16,16,2) = 512 blocks. More waves per
// block -> more resident waves to cover store-drain stalls (R17 postmortem).
__global__ __launch_bounds__(512) void prg_main(
    const f16* __restrict__ u, const f16* __restrict__ v,
    const f16* __restrict__ W2h, const float* __restrict__ b2,
    float* __restrict__ out)
{
    const int tid  = threadIdx.x;
    const int lane = tid & 63;
    const int w    = tid >> 6;
    const int jb   = blockIdx.x * 64;
    const int ib   = blockIdx.y * 64;
    const int b    = blockIdx.z;

    DECL_GELU_CONSTS

    __shared__ f16 u_lds[64][64];   // 8 KB

    {
        const int row = tid >> 3;
        const int col = (tid & 7) * 8;
        *(uint4*)&u_lds[row][col] =
            *(const uint4*)(u + ((size_t)(b * SDIM + ib + row) * 64 + col));
    }

    const int lg = lane >> 4;
    const int lr = lane & 15;
    const int k0 = lg * 8;
    const int jw = jb + (w & 3) * 16;     // wave's j-frag
    const int iw = (w >> 2) * 32;         // wave's i-range base (32 ils)

    const f16* vp = v + ((size_t)(b * SDIM + jw + lr) * 64);
    const uint4 vlo = *(const uint4*)(vp + k0);
    const uint4 vhi = *(const uint4*)(vp + k0 + 32);

    FragH w2lo, w2hi;
    w2lo.q = *(const uint4*)(W2h + lr * 64 + k0);
    w2hi.q = *(const uint4*)(W2h + lr * 64 + k0 + 32);

    const float b2h = b2[lr];

    __syncthreads();

    float* ob = out + ((size_t)(b * 16 + lr) * SDIM + (ib + iw)) * SDIM + jw + lg * 4;

#define GM(IL, ACC)                                                               \
    {                                                                             \
        const uint4 alo = *(const uint4*)&u_lds[IL][k0];                          \
        const uint4 ahi = *(const uint4*)&u_lds[IL][k0 + 32];                     \
        FragH glo, ghi;                                                           \
        glo.u[0] = addgelu_pair(alo.x, vlo.x, GELU_CONSTS);                       \
        glo.u[1] = addgelu_pair(alo.y, vlo.y, GELU_CONSTS);                       \
        glo.u[2] = addgelu_pair(alo.z, vlo.z, GELU_CONSTS);                       \
        glo.u[3] = addgelu_pair(alo.w, vlo.w, GELU_CONSTS);                       \
        ghi.u[0] = addgelu_pair(ahi.x, vhi.x, GELU_CONSTS);                       \
        ghi.u[1] = addgelu_pair(ahi.y, vhi.y, GELU_CONSTS);                       \
        ghi.u[2] = addgelu_pair(ahi.z, vhi.z, GELU_CONSTS);                       \
        ghi.u[3] = addgelu_pair(ahi.w, vhi.w, GELU_CONSTS);                       \
        f32x4 a_ = {b2h, b2h, b2h, b2h};                                          \
        a_ = __builtin_amdgcn_mfma_f32_16x16x32_f16(glo.f, w2lo.f, a_, 0, 0, 0);  \
        a_ = __builtin_amdgcn_mfma_f32_16x16x32_f16(ghi.f, w2hi.f, a_, 0, 0, 0);  \
        ACC = a_;                                                                 \
    }
#define ST(IL, ACC) *(float4*)(ob + (size_t)(IL) * SDIM) = *(float4*)&(ACC);

    f32x4 accA, accB;
    GM(iw + 0, accA)
    #pragma unroll
    for (int p = 0; p < 15; ++p) {
        GM(iw + 2 * p + 1, accB)
        ST(2 * p, accA)
        GM(iw + 2 * p + 2, accA)
        ST(2 * p + 1, accB)
    }
    GM(iw + 31, accB)
    ST(30, accA)
    ST(31, accB)
#undef GM
#undef ST
}

extern "C" void kernel_launch(void* const* d_in, const int* in_sizes, int n_in,
                              void* d_out, int out_size, void* d_ws, size_t ws_size,
                              hipStream_t stream) {
    const float* x  = (const float*)d_in[0];
    const float* Wc = (const float*)d_in[1];
    const float* bc = (const float*)d_in[2];
    const float* W1 = (const float*)d_in[3];
    const float* b1 = (const float*)d_in[4];
    const float* W2 = (const float*)d_in[5];
    const float* b2 = (const float*)d_in[6];
    float* out = (float*)d_out;

    f16* u   = (f16*)d_ws;
    f16* v   = u + 2 * SDIM * 64;
    f16* W2h = v + 2 * SDIM * 64;

    compute_uv<<<dim3(512), dim3(256), 0, stream>>>(x, Wc, bc, W1, b1, W2, u, v, W2h);
    prg_main<<<dim3(16, 16, 2), dim3(512), 0, stream>>>(u, v, W2h, b2, out);
}

// Round 20
// 46.929 us; speedup vs baseline: 8.5370x; 1.0036x over previous
//
#include <hip/hip_runtime.h>
#include <hip/hip_fp16.h>

#define SDIM 1024

typedef _Float16 f16;
typedef _Float16 f16x8 __attribute__((ext_vector_type(8)));
typedef __attribute__((ext_vector_type(4))) float f32x4;

union FragH { unsigned int u[4]; f16x8 f; uint4 q; };

constexpr unsigned short f16bits(float x) {
    return __builtin_bit_cast(unsigned short, (_Float16)x);
}
constexpr unsigned int pk2(float x) {
    return (unsigned int)f16bits(x) * 0x10001u;
}

// 12-instruction trans-free poly gelu (see R18).
__device__ __forceinline__ unsigned int addgelu_pair(
    unsigned int au, unsigned int bu,
    unsigned int sLo, unsigned int sHi, unsigned int sXA, unsigned int vXB,
    unsigned int sC5, unsigned int vC4, unsigned int sC3, unsigned int sC2,
    unsigned int sC1, unsigned int sC0, unsigned int sHalf)
{
    unsigned int g, t, tc, x, w;
    asm("v_pk_add_f16 %1, %5, %6\n\t"
        "v_pk_max_f16 %2, %1, %7\n\t"
        "v_pk_min_f16 %2, %2, %8\n\t"
        "v_pk_mul_f16 %3, %2, %2\n\t"
        "v_pk_fma_f16 %3, %3, %9, %10\n\t"
        "v_pk_fma_f16 %4, %3, %11, %12\n\t"
        "v_pk_fma_f16 %4, %4, %3, %13\n\t"
        "v_pk_fma_f16 %4, %4, %3, %14\n\t"
        "v_pk_fma_f16 %4, %4, %3, %15\n\t"
        "v_pk_fma_f16 %4, %4, %3, %16\n\t"
        "v_pk_fma_f16 %4, %4, %2, %17\n\t"
        "v_pk_mul_f16 %0, %1, %4"
        : "=v"(g), "=&v"(t), "=&v"(tc), "=&v"(x), "=&v"(w)
        : "v"(au), "v"(bu),
          "s"(sLo), "s"(sHi), "s"(sXA), "v"(vXB),
          "s"(sC5), "v"(vC4), "s"(sC3), "s"(sC2), "s"(sC1), "s"(sC0), "s"(sHalf));
    return g;
}

#define GELU_CONSTS  kLo, kHi, kXA, kXB, kC5, kC4, kC3, kC2, kC1, kC0, kHalf
#define DECL_GELU_CONSTS \
    const unsigned int kLo   = pk2(-3.0f); \
    const unsigned int kHi   = pk2( 3.0f); \
    const unsigned int kXA   = pk2( 2.0f / 9.0f); \
    const unsigned int kXB   = pk2(-1.0f); \
    const unsigned int kC5   = pk2(-0.003456f); \
    const unsigned int kC4   = pk2( 0.009668f); \
    const unsigned int kC3   = pk2(-0.020158f); \
    const unsigned int kC2   = pk2( 0.045110f); \
    const unsigned int kC1   = pk2(-0.092726f); \
    const unsigned int kC0   = pk2( 0.2278245f); \
    const unsigned int kHalf = pk2( 0.5f);

// ---------------- Kernel 1: u,v f16 + W2h = W2^T f16 [16h][64k] ----------------
__global__ __launch_bounds__(256) void compute_uv(
    const float* __restrict__ x, const float* __restrict__ Wc,
    const float* __restrict__ bc, const float* __restrict__ W1,
    const float* __restrict__ b1, const float* __restrict__ W2,
    f16* __restrict__ u, f16* __restrict__ v, f16* __restrict__ W2h)
{
    __shared__ float xrow[4 * 1024];
    __shared__ float part[4 * 8 * 32];
    __shared__ float xc[4 * 32];
    const int tid = threadIdx.x;
    const size_t bs0 = (size_t)blockIdx.x * 4;

    if (blockIdx.x == 0) {
        #pragma unroll
        for (int e = 0; e < 4; ++e) {
            const int flat = tid * 4 + e;
            const int h = flat >> 6, k = flat & 63;
            W2h[flat] = (f16)W2[k * 16 + h];
        }
    }
    const float4* xin = (const float4*)(x + bs0 * 1024);
    #pragma unroll
    for (int it = 0; it < 4; ++it)
        ((float4*)xrow)[it * 256 + tid] = xin[it * 256 + tid];
    __syncthreads();
    {
        const int c = tid & 31, p = tid >> 5;
        float acc[4] = {0.f, 0.f, 0.f, 0.f};
        #pragma unroll 4
        for (int dd = 0; dd < 128; ++dd) {
            const int d = p * 128 + dd;
            const float wv = Wc[d * 32 + c];
            #pragma unroll
            for (int r = 0; r < 4; ++r)
                acc[r] = __builtin_fmaf(xrow[r * 1024 + d], wv, acc[r]);
        }
        #pragma unroll
        for (int r = 0; r < 4; ++r)
            part[r * 256 + p * 32 + c] = acc[r];
    }
    __syncthreads();
    if (tid < 128) {
        const int r = tid >> 5, c = tid & 31;
        float s = bc[c];
        #pragma unroll
        for (int p = 0; p < 8; ++p) s += part[r * 256 + p * 32 + c];
        xc[r * 32 + c] = s;
    }
    __syncthreads();
    {
        const int h = tid & 63;
        const int rr = tid >> 6;
        float ua = b1[h], va = 0.0f;
        #pragma unroll
        for (int cc = 0; cc < 32; ++cc) {
            const float xv = xc[rr * 32 + cc];
            ua = __builtin_fmaf(xv, W1[cc * 64 + h], ua);
            va = __builtin_fmaf(xv, W1[(32 + cc) * 64 + h], va);
        }
        u[(bs0 + rr) * 64 + h] = (f16)ua;
        v[(bs0 + rr) * 64 + h] = (f16)va;
    }
}

// ---------------- Kernel 2: out[b,h,i,j] = sum_k gelu(u[i,k]+v[j,k])*W2[k,h] + b2[h] --
// R18 tile (64i x 64j, 512 thr, 8 waves, 32 il/wave), grid (16,16,2), C stores,
// 2-deep acc pipeline. NEW: distance-1 LDS prefetch — il+1's ds_read_b128 pair is
// issued into dedicated registers BEFORE il's gelu chain, hiding the ~120cy LDS
// latency that R8's counters show as the 21% VALU-idle gap (VALUBusy 79%).
__global__ __launch_bounds__(512) void prg_main(
    const f16* __restrict__ u, const f16* __restrict__ v,
    const f16* __restrict__ W2h, const float* __restrict__ b2,
    float* __restrict__ out)
{
    const int tid  = threadIdx.x;
    const int lane = tid & 63;
    const int w    = tid >> 6;
    const int jb   = blockIdx.x * 64;
    const int ib   = blockIdx.y * 64;
    const int b    = blockIdx.z;

    DECL_GELU_CONSTS

    __shared__ f16 u_lds[64][64];   // 8 KB

    {
        const int row = tid >> 3;
        const int col = (tid & 7) * 8;
        *(uint4*)&u_lds[row][col] =
            *(const uint4*)(u + ((size_t)(b * SDIM + ib + row) * 64 + col));
    }

    const int lg = lane >> 4;
    const int lr = lane & 15;
    const int k0 = lg * 8;
    const int jw = jb + (w & 3) * 16;
    const int iw = (w >> 2) * 32;

    const f16* vp = v + ((size_t)(b * SDIM + jw + lr) * 64);
    const uint4 vlo = *(const uint4*)(vp + k0);
    const uint4 vhi = *(const uint4*)(vp + k0 + 32);

    FragH w2lo, w2hi;
    w2lo.q = *(const uint4*)(W2h + lr * 64 + k0);
    w2hi.q = *(const uint4*)(W2h + lr * 64 + k0 + 32);

    const float b2h = b2[lr];

    __syncthreads();

    float* ob = out + ((size_t)(b * 16 + lr) * SDIM + (ib + iw)) * SDIM + jw + lg * 4;

#define LD(IL, ALO, AHI)                                                          \
    ALO = *(const uint4*)&u_lds[IL][k0];                                          \
    AHI = *(const uint4*)&u_lds[IL][k0 + 32];

#define CM(ALO, AHI, ACC)                                                         \
    {                                                                             \
        FragH glo, ghi;                                                           \
        glo.u[0] = addgelu_pair(ALO.x, vlo.x, GELU_CONSTS);                       \
        glo.u[1] = addgelu_pair(ALO.y, vlo.y, GELU_CONSTS);                       \
        glo.u[2] = addgelu_pair(ALO.z, vlo.z, GELU_CONSTS);                       \
        glo.u[3] = addgelu_pair(ALO.w, vlo.w, GELU_CONSTS);                       \
        ghi.u[0] = addgelu_pair(AHI.x, vhi.x, GELU_CONSTS);                       \
        ghi.u[1] = addgelu_pair(AHI.y, vhi.y, GELU_CONSTS);                       \
        ghi.u[2] = addgelu_pair(AHI.z, vhi.z, GELU_CONSTS);                       \
        ghi.u[3] = addgelu_pair(AHI.w, vhi.w, GELU_CONSTS);                       \
        f32x4 a_ = {b2h, b2h, b2h, b2h};                                          \
        a_ = __builtin_amdgcn_mfma_f32_16x16x32_f16(glo.f, w2lo.f, a_, 0, 0, 0);  \
        a_ = __builtin_amdgcn_mfma_f32_16x16x32_f16(ghi.f, w2hi.f, a_, 0, 0, 0);  \
        ACC = a_;                                                                 \
    }
#define ST(IL, ACC) *(float4*)(ob + (size_t)(IL) * SDIM) = *(float4*)&(ACC);

    uint4 lo0, hi0, lo1, hi1;
    f32x4 accA, accB;
    LD(iw + 0, lo0, hi0)
    LD(iw + 1, lo1, hi1)
    CM(lo0, hi0, accA)
    #pragma unroll
    for (int p = 0; p < 15; ++p) {
        LD(iw + 2 * p + 2, lo0, hi0)     // prefetch il+1 before computing il
        CM(lo1, hi1, accB)
        ST(2 * p, accA)
        LD(iw + 2 * p + 3, lo1, hi1)
        CM(lo0, hi0, accA)
        ST(2 * p + 1, accB)
    }
    CM(lo1, hi1, accB)
    ST(30, accA)
    ST(31, accB)
#undef LD
#undef CM
#undef ST
}

extern "C" void kernel_launch(void* const* d_in, const int* in_sizes, int n_in,
                              void* d_out, int out_size, void* d_ws, size_t ws_size,
                              hipStream_t stream) {
    const float* x  = (const float*)d_in[0];
    const float* Wc = (const float*)d_in[1];
    const float* bc = (const float*)d_in[2];
    const float* W1 = (const float*)d_in[3];
    const float* b1 = (const float*)d_in[4];
    const float* W2 = (const float*)d_in[5];
    const float* b2 = (const float*)d_in[6];
    float* out = (float*)d_out;

    f16* u   = (f16*)d_ws;
    f16* v   = u + 2 * SDIM * 64;
    f16* W2h = v + 2 * SDIM * 64;

    compute_uv<<<dim3(512), dim3(256), 0, stream>>>(x, Wc, bc, W1, b1, W2, u, v, W2h);
    prg_main<<<dim3(16, 16, 2), dim3(512), 0, stream>>>(u, v, W2h, b2, out);
}